// Round 11
// baseline (9101.437 us; speedup 1.0000x reference)
//
#include <hip/hip_runtime.h>

#define ATOM  14
#define BOND  3
#define INNER 20
#define HID   34
#define REC   20
#define OHID  25
#define NN    1048576
#define NE    983040
#define NG    16384
#define NBIN  32            // bin = 2*depth + (leaf?1:0)
#define LVL_CAP 131072      // max nodes per depth (mean 65536, 2x safety)

#define NB    512
#define NT    256
#define GT    (NB*NT)       // 131072
#define SPAN  (NN/NB)       // 2048
#define SE    (SPAN/NT)     // 8

__device__ __forceinline__ float leaky(float x) { return x >= 0.f ? x : 0.01f * x; }

// ---- coherent (agent-scope, L2-bypassing) 8-byte msg accessors ----
union F2U { float2 f; unsigned long long u; };
__device__ __forceinline__ void st2(float* p, float x, float y) {
    F2U t; t.f = make_float2(x, y);
    __hip_atomic_store((unsigned long long*)p, t.u, __ATOMIC_RELAXED, __HIP_MEMORY_SCOPE_AGENT);
}
__device__ __forceinline__ float2 ld2(const float* p) {
    F2U t;
    t.u = __hip_atomic_load((const unsigned long long*)p, __ATOMIC_RELAXED, __HIP_MEMORY_SCOPE_AGENT);
    return t.f;
}

// heavy barrier (prep): full fences, conservative
__device__ __forceinline__ void gbar_f(int* bar, int goal) {
    __syncthreads();
    if (threadIdx.x == 0) {
        __threadfence();
        __hip_atomic_fetch_add(bar, 1, __ATOMIC_RELEASE, __HIP_MEMORY_SCOPE_AGENT);
        while (__hip_atomic_load(bar, __ATOMIC_RELAXED, __HIP_MEMORY_SCOPE_AGENT) < goal)
            __builtin_amdgcn_s_sleep(32);
        __threadfence();
    }
    __syncthreads();
}

// light barrier (levels): release-add / acquire-spin only.
// Correct because ALL cross-phase data goes through agent-scope atomics
// (msg via st2/ld2, g via atomicAdd) -> nothing dirty in per-XCD L2.
__device__ __forceinline__ void gbar_l(int* bar, int goal) {
    __syncthreads();
    if (threadIdx.x == 0) {
        __hip_atomic_fetch_add(bar, 1, __ATOMIC_RELEASE, __HIP_MEMORY_SCOPE_AGENT);
        while (__hip_atomic_load(bar, __ATOMIC_ACQUIRE, __HIP_MEMORY_SCOPE_AGENT) < goal)
            __builtin_amdgcn_s_sleep(32);
    }
    __syncthreads();
}

__global__ void k_pre(int* cnt_n, int* pp_s, float* g, int* cnt32, int* adj_total, int* bars) {
    int tid = blockIdx.x * 256 + threadIdx.x;           // 1024 blocks -> 262144 threads
    for (int i = tid; i < NN; i += 262144) { cnt_n[i] = 0; pp_s[i] = -1; }
    for (int i = tid; i < NG * REC; i += 262144) g[i] = 0.f;
    if (tid < NBIN) cnt32[tid << 4] = 0;
    if (tid == NBIN) *adj_total = 0;
    if (tid == NBIN + 1) { bars[0] = 0; bars[16] = 0; }
}

// ---------------- prep: counts, sort, CSR ----------------
__global__ __launch_bounds__(NT) void k_prep(
    const int* __restrict__ parent, const int* __restrict__ child,
    const int* __restrict__ depth, const int* __restrict__ gid,
    const float* __restrict__ isr, const float* __restrict__ bond,
    int* cnt_n, int* node_list, int* inv, int* groot_s, int* cnt_s,
    int* row_ptr, int* cur, int* pp_s, int* adjc, float4* bond_s4,
    int* cnt32, int* blkbase, int* adj_total, int* bar)
{
    __shared__ int sh[NT];
    __shared__ int soff[NBIN + 1];
    __shared__ int lh[NBIN];
    __shared__ int lbase[NBIN];
    __shared__ int sbase;
    const int t = threadIdx.x;
    const int tid = blockIdx.x * NT + t;
    const int span0 = blockIdx.x * SPAN;
    int ep = 0;

    // P0: per-node child counts
    for (int e = tid; e < NE; e += GT) atomicAdd(&cnt_n[parent[e]], 1);
    gbar_f(bar, NB * ++ep);

    // P1: per-block depth-major histogram; one global atomic per (block,bin)
    if (t < NBIN) lh[t] = 0;
    __syncthreads();
    for (int i = span0 + t; i < span0 + SPAN; i += NT) {
        int b = 2 * depth[i] + (cnt_n[i] == 0 ? 1 : 0);
        atomicAdd(&lh[b], 1);
    }
    __syncthreads();
    if (t < NBIN) blkbase[blockIdx.x * NBIN + t] = atomicAdd(&cnt32[t << 4], lh[t]);
    gbar_f(bar, NB * ++ep);

    // P2: scatter (counting sort); per-position metadata written at pos
    if (t == 0) {
        int s = 0;
        for (int b = 0; b < NBIN; ++b) { soff[b] = s; s += cnt32[b << 4]; }
        soff[NBIN] = s;
    }
    if (t < NBIN) { lbase[t] = blkbase[blockIdx.x * NBIN + t]; lh[t] = 0; }
    __syncthreads();
    for (int i = span0 + t; i < span0 + SPAN; i += NT) {
        int cn = cnt_n[i];
        int b = 2 * depth[i] + (cn == 0 ? 1 : 0);
        int r = atomicAdd(&lh[b], 1);
        int pos = soff[b] + lbase[b] + r;
        node_list[pos] = i;
        inv[i] = pos;
        groot_s[pos] = (isr[i] != 0.f) ? gid[i] : -1;
        cnt_s[pos] = cn;
    }
    gbar_f(bar, NB * ++ep);

    // P3: row_ptr via span-local scan + orderless global base; cur = copy
    {
        int base0 = span0 + t * SE;
        int v[SE]; int sum = 0;
        #pragma unroll
        for (int k = 0; k < SE; ++k) { v[k] = cnt_s[base0 + k]; sum += v[k]; }
        sh[t] = sum;
        __syncthreads();
        for (int ofs = 1; ofs < NT; ofs <<= 1) {
            int x = (t >= ofs) ? sh[t - ofs] : 0;
            __syncthreads();
            sh[t] += x;
            __syncthreads();
        }
        if (t == NT - 1) sbase = atomicAdd(adj_total, sh[t]);
        __syncthreads();
        int run = sbase + sh[t] - sum;
        #pragma unroll
        for (int k = 0; k < SE; ++k) { row_ptr[base0 + k] = run; cur[base0 + k] = run; run += v[k]; }
    }
    gbar_f(bar, NB * ++ep);

    // P4: edge pass 2 — adjc direct fill + per-child data
    for (int e = tid; e < NE; e += GT) {
        int cpos = inv[child[e]];
        int pp   = inv[parent[e]];
        int slot = atomicAdd(&cur[pp], 1);
        adjc[slot] = cpos;
        pp_s[cpos] = pp;
        bond_s4[cpos] = make_float4(bond[(size_t)e * BOND], bond[(size_t)e * BOND + 1],
                                    bond[(size_t)e * BOND + 2], 0.f);
    }
}

// ---------------- levels: 16 depth phases, msg double-buffer ----------------
__device__ __forceinline__ void emit(int pos, int slot, int pp, int gr,
                                     const float* __restrict__ o,
                                     const float4* __restrict__ bond_s4,
                                     const float* __restrict__ iw,
                                     const float* __restrict__ ib,
                                     float* __restrict__ g, float* __restrict__ wbuf) {
    if (gr >= 0) {
        float* gp = g + (size_t)gr * REC;
        #pragma unroll
        for (int j = 0; j < REC; ++j) atomicAdd(&gp[j], o[j]);
    }
    if (pp >= 0) {
        float4 b4 = bond_s4[pos];
        float m[INNER];
        #pragma unroll
        for (int j = 0; j < INNER; ++j)
            m[j] = ib[j] + b4.x * iw[0 * INNER + j] + b4.y * iw[1 * INNER + j]
                         + b4.z * iw[2 * INNER + j];
        #pragma unroll
        for (int k = 0; k < REC; ++k) {
            float ok = o[k];
            #pragma unroll
            for (int j = 0; j < INNER; ++j) m[j] += ok * iw[(BOND + k) * INNER + j];
        }
        float* mp = wbuf + (size_t)slot * REC;
        #pragma unroll
        for (int j = 0; j < 10; ++j)
            st2(mp + 2 * j, leaky(m[2*j]), leaky(m[2*j+1]));
    }
}

__global__ __launch_bounds__(NT) void k_levels(
    const float* __restrict__ atom,
    const int* __restrict__ node_list, const int* __restrict__ pp_s,
    const int* __restrict__ groot_s, const int* __restrict__ cnt_s,
    const int* __restrict__ row_ptr, const int* __restrict__ adjc,
    const float4* __restrict__ bond_s4,
    const float* __restrict__ iw, const float* __restrict__ ib,
    const float* __restrict__ nw1, const float* __restrict__ nb1,
    const float* __restrict__ nw2, const float* __restrict__ nb2,
    const float* __restrict__ l0w1, const float* __restrict__ l0b1,
    const float* __restrict__ l0w2, const float* __restrict__ l0b2,
    float* __restrict__ g, float* buf0, float* buf1,
    const int* __restrict__ cnt32, int* bar)
{
    __shared__ int soff[NBIN + 1];
    const int t = threadIdx.x;
    const int tid = blockIdx.x * NT + t;
    int ep = 0;
    if (t == 0) {
        int s = 0;
        for (int b = 0; b < NBIN; ++b) { soff[b] = s; s += cnt32[b << 4]; }
        soff[NBIN] = s;
    }
    __syncthreads();

    for (int D = 15; D >= 0; --D) {
        int base = soff[2 * D];
        int limI = soff[2 * D + 1];
        int limA = soff[2 * D + 2];
        int cbase = (D < 15) ? soff[2 * D + 2] : 0;   // children-depth base
        float* wbuf = (D & 1) ? buf1 : buf0;
        const float* rbuf = (D & 1) ? buf0 : buf1;

        // internal nodes at depth D (uniform waves)
        for (int pos = base + tid; pos < limI; pos += GT) {
            int n   = cnt_s[pos];
            int i   = node_list[pos];
            int pp  = pp_s[pos];
            int gr  = groot_s[pos];
            int rp0 = row_ptr[pos];
            const float2* a2 = (const float2*)(atom + (size_t)i * ATOM);
            float a[ATOM];
            #pragma unroll
            for (int k = 0; k < 7; ++k) { float2 v = a2[k]; a[2*k] = v.x; a[2*k+1] = v.y; }
            float isum[INNER];
            #pragma unroll
            for (int j = 0; j < INNER; ++j) isum[j] = 0.f;
            for (int r = rp0; r < rp0 + n; ++r) {
                int c = adjc[r] - cbase;
                const float* mp = rbuf + (size_t)c * REC;
                #pragma unroll
                for (int q = 0; q < 10; ++q) {
                    float2 v = ld2(mp + 2 * q);
                    isum[2*q]   += v.x;
                    isum[2*q+1] += v.y;
                }
            }
            float hid[HID];
            #pragma unroll
            for (int j = 0; j < HID; ++j) hid[j] = nb1[j];
            for (int k = 0; k < ATOM; ++k) {
                float xk = a[k];
                #pragma unroll
                for (int j = 0; j < HID; ++j) hid[j] += xk * nw1[k * HID + j];
            }
            for (int k = 0; k < INNER; ++k) {
                float xk = isum[k];
                #pragma unroll
                for (int j = 0; j < HID; ++j) hid[j] += xk * nw1[(ATOM + k) * HID + j];
            }
            #pragma unroll
            for (int j = 0; j < HID; ++j) hid[j] = leaky(hid[j]);
            float o[REC];
            #pragma unroll
            for (int j = 0; j < REC; ++j) o[j] = nb2[j];
            for (int k = 0; k < HID; ++k) {
                float hk = hid[k];
                #pragma unroll
                for (int j = 0; j < REC; ++j) o[j] += hk * nw2[k * REC + j];
            }
            #pragma unroll
            for (int j = 0; j < REC; ++j) o[j] = leaky(o[j]);
            emit(pos, pos - base, pp, gr, o, bond_s4, iw, ib, g, wbuf);
        }

        // leaves at depth D (uniform waves)
        for (int pos = limI + tid; pos < limA; pos += GT) {
            int i  = node_list[pos];
            int pp = pp_s[pos];
            int gr = groot_s[pos];
            const float2* a2 = (const float2*)(atom + (size_t)i * ATOM);
            float a[ATOM];
            #pragma unroll
            for (int k = 0; k < 7; ++k) { float2 v = a2[k]; a[2*k] = v.x; a[2*k+1] = v.y; }
            float hid[HID];
            #pragma unroll
            for (int j = 0; j < HID; ++j) hid[j] = l0b1[j];
            for (int k = 0; k < ATOM; ++k) {
                float ak = a[k];
                #pragma unroll
                for (int j = 0; j < HID; ++j) hid[j] += ak * l0w1[k * HID + j];
            }
            #pragma unroll
            for (int j = 0; j < HID; ++j) hid[j] = leaky(hid[j]);
            float o[REC];
            #pragma unroll
            for (int j = 0; j < REC; ++j) o[j] = l0b2[j];
            for (int k = 0; k < HID; ++k) {
                float hk = hid[k];
                #pragma unroll
                for (int j = 0; j < REC; ++j) o[j] += hk * l0w2[k * REC + j];
            }
            #pragma unroll
            for (int j = 0; j < REC; ++j) o[j] = leaky(o[j]);
            emit(pos, pos - base, pp, gr, o, bond_s4, iw, ib, g, wbuf);
        }
        if (D) gbar_l(bar, NB * ++ep);
    }
}

// ---------------- readout ----------------
__global__ void k_out(const float* __restrict__ g,
                      const float* __restrict__ w1, const float* __restrict__ b1,
                      const float* __restrict__ w2, const float* __restrict__ b2,
                      float* __restrict__ out) {
    int t = blockIdx.x * 256 + threadIdx.x;
    if (t >= NG) return;
    const float* gv = g + (size_t)t * REC;
    float gl[REC];
    #pragma unroll
    for (int k = 0; k < REC; ++k) gl[k] = gv[k];
    float acc = b2[0];
    for (int j = 0; j < OHID; ++j) {
        float s = b1[j];
        #pragma unroll
        for (int k = 0; k < REC; ++k) s += gl[k] * w1[k * OHID + j];
        acc += tanhf(s) * w2[j];
    }
    out[t] = acc;
}

extern "C" void kernel_launch(void* const* d_in, const int* in_sizes, int n_in,
                              void* d_out, int out_size, void* d_ws, size_t ws_size,
                              hipStream_t stream) {
    const float* atom    = (const float*)d_in[0];
    const float* bond    = (const float*)d_in[1];
    const int*   parent  = (const int*)d_in[2];
    const int*   child   = (const int*)d_in[3];
    const int*   depth   = (const int*)d_in[4];
    const int*   gid     = (const int*)d_in[5];
    const float* isr     = (const float*)d_in[6];
    const float* inner_w = (const float*)d_in[7];
    const float* inner_b = (const float*)d_in[8];
    const float* net_w1  = (const float*)d_in[9];
    const float* net_b1  = (const float*)d_in[10];
    const float* net_w2  = (const float*)d_in[11];
    const float* net_b2  = (const float*)d_in[12];
    const float* net0_w1 = (const float*)d_in[13];
    const float* net0_b1 = (const float*)d_in[14];
    const float* net0_w2 = (const float*)d_in[15];
    const float* net0_b2 = (const float*)d_in[16];
    const float* out_w1  = (const float*)d_in[17];
    const float* out_b1  = (const float*)d_in[18];
    const float* out_w2  = (const float*)d_in[19];
    const float* out_b2  = (const float*)d_in[20];
    float* out = (float*)d_out;

    char* ws = (char*)d_ws;
    size_t o = 0;
    float* buf0     = (float*)(ws + o);  o += (size_t)LVL_CAP * REC * 4;  // 10.5 MB
    float* buf1     = (float*)(ws + o);  o += (size_t)LVL_CAP * REC * 4;  // 10.5 MB
    float* g        = (float*)(ws + o);  o += (size_t)NG * REC * 4;       // 1.3 MB
    float4* bond_s4 = (float4*)(ws + o); o += (size_t)NN * 16;            // 16.8 MB
    int* cnt_n      = (int*)(ws + o);    o += (size_t)NN * 4;             // 4.2 MB
    int* node_list  = (int*)(ws + o);    o += (size_t)NN * 4;
    int* inv        = (int*)(ws + o);    o += (size_t)NN * 4;
    int* groot_s    = (int*)(ws + o);    o += (size_t)NN * 4;
    int* cnt_s      = (int*)(ws + o);    o += (size_t)NN * 4;
    int* row_ptr    = (int*)(ws + o);    o += (size_t)NN * 4;
    int* cur        = (int*)(ws + o);    o += (size_t)NN * 4;
    int* pp_s       = (int*)(ws + o);    o += (size_t)NN * 4;
    int* adjc       = (int*)(ws + o);    o += (size_t)NE * 4;             // 3.9 MB
    int* blkbase    = (int*)(ws + o);    o += (size_t)NB * NBIN * 4;      // 64 KB
    int* cnt32      = (int*)(ws + o);    o += NBIN * 16 * 4;
    int* adj_total  = (int*)(ws + o);    o += 64;
    int* bars       = (int*)(ws + o);    o += 256;
    // total ~78 MB

    k_pre<<<1024, 256, 0, stream>>>(cnt_n, pp_s, g, cnt32, adj_total, bars);
    k_prep<<<NB, NT, 0, stream>>>(parent, child, depth, gid, isr, bond,
                                  cnt_n, node_list, inv, groot_s, cnt_s,
                                  row_ptr, cur, pp_s, adjc, bond_s4,
                                  cnt32, blkbase, adj_total, &bars[0]);
    k_levels<<<NB, NT, 0, stream>>>(atom, node_list, pp_s, groot_s, cnt_s,
                                    row_ptr, adjc, bond_s4,
                                    inner_w, inner_b, net_w1, net_b1, net_w2, net_b2,
                                    net0_w1, net0_b1, net0_w2, net0_b2,
                                    g, buf0, buf1, cnt32, &bars[16]);
    k_out<<<(NG + 255) / 256, 256, 0, stream>>>(g, out_w1, out_b1, out_w2, out_b2, out);
}

// Round 12
// 2740.796 us; speedup vs baseline: 3.3207x; 3.3207x over previous
//
#include <hip/hip_runtime.h>

#define ATOM  14
#define BOND  3
#define INNER 20
#define HID   34
#define REC   20
#define OHID  25
#define NN    1048576
#define NE    983040
#define NG    16384

#define NB    512            // prep persistent grid
#define NT    256
#define GT    (NB*NT)        // 131072
#define SPAN  (NN/NB)        // 2048
#define SE    (SPAN/NT)      // 8

#define NB2   1024           // level blocks (independent, not cooperative)
#define NT2   128
#define NBINS (NB2*32)       // bin = blk*32 + depth*2 + isLeaf

__device__ __forceinline__ float leaky(float x) { return x >= 0.f ? x : 0.01f * x; }

// grid-wide barrier for prep only: device-scope fences (cross-XCD safe)
__device__ __forceinline__ void gbar_f(int* bar, int goal) {
    __syncthreads();
    if (threadIdx.x == 0) {
        __threadfence();
        __hip_atomic_fetch_add(bar, 1, __ATOMIC_RELEASE, __HIP_MEMORY_SCOPE_AGENT);
        while (__hip_atomic_load(bar, __ATOMIC_RELAXED, __HIP_MEMORY_SCOPE_AGENT) < goal)
            __builtin_amdgcn_s_sleep(32);
        __threadfence();
    }
    __syncthreads();
}

__global__ void k_pre(int* cnt_n, int* pnode, float* g, int* bin_cnt, int* totals, int* bars) {
    int tid = blockIdx.x * 256 + threadIdx.x;          // 262144 threads
    for (int i = tid; i < NN; i += 262144) { cnt_n[i] = 0; pnode[i] = i; }
    for (int i = tid; i < NG * REC; i += 262144) g[i] = 0.f;
    for (int i = tid; i < NBINS; i += 262144) bin_cnt[i] = 0;
    if (tid == 0) { totals[0] = 0; totals[16] = 0; }
    if (tid == 1) for (int k = 0; k < 32; ++k) bars[k] = 0;
}

// ---------------- prep: counts, roots, sort, CSR ----------------
__global__ __launch_bounds__(NT) void k_prep(
    const int* __restrict__ parent, const int* __restrict__ child,
    const int* __restrict__ depth, const int* __restrict__ gid,
    const float* __restrict__ isr, const float* __restrict__ bond,
    int* cnt_n,            // also cur2 (P8+)
    int* pnode,            // also node_list (P7+)
    int* r1,               // also inv (P7+)
    int* r2,               // also groot_s (P7+)
    int* K_s, int* cnt_s, int* row_ptr, int* adjc, float4* bond_s4,
    int* bin_cnt, int* bin_base, int* bin_cur,
    int* totals, int* bar)
{
    __shared__ int sh[NT];
    __shared__ int sbase_sh;
    const int t = threadIdx.x;
    const int tid = blockIdx.x * NT + t;
    int ep = 0;

    // P0: child counts + parent pointers
    for (int e = tid; e < NE; e += GT) {
        atomicAdd(&cnt_n[parent[e]], 1);
        pnode[child[e]] = parent[e];
    }
    gbar_f(bar, NB * ++ep);

    // P1-P4: pointer doubling -> r2 = root (covers 16 levels)
    for (int i = tid; i < NN; i += GT) r1[i] = pnode[pnode[i]];
    gbar_f(bar, NB * ++ep);
    for (int i = tid; i < NN; i += GT) r2[i] = r1[r1[i]];
    gbar_f(bar, NB * ++ep);
    for (int i = tid; i < NN; i += GT) r1[i] = r2[r2[i]];
    gbar_f(bar, NB * ++ep);
    for (int i = tid; i < NN; i += GT) r2[i] = r1[r1[i]];
    gbar_f(bar, NB * ++ep);

    // P5: bin key + histogram
    for (int i = tid; i < NN; i += GT) {
        int K = (r2[i] & (NB2 - 1)) * 32 + depth[i] * 2 + (cnt_n[i] == 0 ? 1 : 0);
        K_s[i] = K;
        atomicAdd(&bin_cnt[K], 1);
    }
    gbar_f(bar, NB * ++ep);

    // P6: bin scan (orderless base): blocks 0..127, 256 bins each
    if (blockIdx.x < NBINS / NT) {
        int k0 = blockIdx.x * NT + t;
        int v = bin_cnt[k0];
        sh[t] = v;
        __syncthreads();
        for (int ofs = 1; ofs < NT; ofs <<= 1) {
            int x = (t >= ofs) ? sh[t - ofs] : 0;
            __syncthreads();
            sh[t] += x;
            __syncthreads();
        }
        if (t == NT - 1) sbase_sh = atomicAdd(&totals[0], sh[t]);
        __syncthreads();
        int b = sbase_sh + sh[t] - v;
        bin_base[k0] = b;
        bin_cur[k0] = b;
    }
    gbar_f(bar, NB * ++ep);

    // P7: scatter (counting sort); NOTE node_list/inv/groot_s alias pnode/r1/r2
    for (int i = tid; i < NN; i += GT) {
        int pos = atomicAdd(&bin_cur[K_s[i]], 1);
        pnode[pos] = i;                                 // node_list
        r1[i] = pos;                                    // inv
        r2[pos] = (isr[i] != 0.f) ? gid[i] : -1;        // groot_s
        cnt_s[pos] = cnt_n[i];
    }
    gbar_f(bar, NB * ++ep);

    // P8: row_ptr via span scan + orderless base; cur2 (aliases cnt_n) = copy
    {
        int base0 = blockIdx.x * SPAN + t * SE;
        int v[SE]; int sum = 0;
        #pragma unroll
        for (int k = 0; k < SE; ++k) { v[k] = cnt_s[base0 + k]; sum += v[k]; }
        __syncthreads();
        sh[t] = sum;
        __syncthreads();
        for (int ofs = 1; ofs < NT; ofs <<= 1) {
            int x = (t >= ofs) ? sh[t - ofs] : 0;
            __syncthreads();
            sh[t] += x;
            __syncthreads();
        }
        if (t == NT - 1) sbase_sh = atomicAdd(&totals[16], sh[t]);
        __syncthreads();
        int run = sbase_sh + sh[t] - sum;
        #pragma unroll
        for (int k = 0; k < SE; ++k) { row_ptr[base0 + k] = run; cnt_n[base0 + k] = run; run += v[k]; }
    }
    gbar_f(bar, NB * ++ep);

    // P9: edge pass 2 — adjc fill + per-child bond
    for (int e = tid; e < NE; e += GT) {
        int cpos = r1[child[e]];                        // inv
        int pp   = r1[parent[e]];
        int slot = atomicAdd(&cnt_n[pp], 1);            // cur2
        adjc[slot] = cpos;
        bond_s4[cpos] = make_float4(bond[(size_t)e * BOND], bond[(size_t)e * BOND + 1],
                                    bond[(size_t)e * BOND + 2], 0.f);
    }
}

// ---------------- levels: independent blocks, block-local msg, NO grid sync ----------------
__global__ __launch_bounds__(NT2) void k_levels(
    const float* __restrict__ atom,
    const int* __restrict__ node_list, const int* __restrict__ groot_s,
    const int* __restrict__ cnt_s, const int* __restrict__ row_ptr,
    const int* __restrict__ adjc, const float4* __restrict__ bond_s4,
    const int* __restrict__ bin_base, const int* __restrict__ bin_cnt,
    const float* __restrict__ iw, const float* __restrict__ ib,
    const float* __restrict__ nw1, const float* __restrict__ nb1,
    const float* __restrict__ nw2, const float* __restrict__ nb2,
    const float* __restrict__ l0w1, const float* __restrict__ l0b1,
    const float* __restrict__ l0w2, const float* __restrict__ l0b2,
    float* __restrict__ g, float* __restrict__ msg_s)
{
    const int t = threadIdx.x;
    const int b = blockIdx.x;

    for (int d = 15; d >= 0; --d) {
        // ---- internal nodes (bin b*32 + d*2) ----
        {
            int K = b * 32 + d * 2;
            int base = bin_base[K], n0 = bin_cnt[K];
            for (int idx = t; idx < n0; idx += NT2) {
                int pos = base + idx;
                int n   = cnt_s[pos];
                int i   = node_list[pos];
                int gr  = groot_s[pos];
                int rp0 = row_ptr[pos];
                const float2* a2 = (const float2*)(atom + (size_t)i * ATOM);
                float a[ATOM];
                #pragma unroll
                for (int k = 0; k < 7; ++k) { float2 v = a2[k]; a[2*k] = v.x; a[2*k+1] = v.y; }
                float isum[INNER];
                #pragma unroll
                for (int j = 0; j < INNER; ++j) isum[j] = 0.f;
                for (int r = rp0; r < rp0 + n; ++r) {
                    int c = adjc[r];
                    const float4* mp = (const float4*)(msg_s + (size_t)c * REC);
                    #pragma unroll
                    for (int q = 0; q < 5; ++q) {
                        float4 v = mp[q];
                        isum[4*q]   += v.x; isum[4*q+1] += v.y;
                        isum[4*q+2] += v.z; isum[4*q+3] += v.w;
                    }
                }
                float hid[HID];
                #pragma unroll
                for (int j = 0; j < HID; ++j) hid[j] = nb1[j];
                for (int k = 0; k < ATOM; ++k) {
                    float xk = a[k];
                    #pragma unroll
                    for (int j = 0; j < HID; ++j) hid[j] += xk * nw1[k * HID + j];
                }
                for (int k = 0; k < INNER; ++k) {
                    float xk = isum[k];
                    #pragma unroll
                    for (int j = 0; j < HID; ++j) hid[j] += xk * nw1[(ATOM + k) * HID + j];
                }
                #pragma unroll
                for (int j = 0; j < HID; ++j) hid[j] = leaky(hid[j]);
                float o[REC];
                #pragma unroll
                for (int j = 0; j < REC; ++j) o[j] = nb2[j];
                for (int k = 0; k < HID; ++k) {
                    float hk = hid[k];
                    #pragma unroll
                    for (int j = 0; j < REC; ++j) o[j] += hk * nw2[k * REC + j];
                }
                #pragma unroll
                for (int j = 0; j < REC; ++j) o[j] = leaky(o[j]);
                if (gr >= 0) {          // root: no parent edge -> readout only
                    float* gp = g + (size_t)gr * REC;
                    #pragma unroll
                    for (int j = 0; j < REC; ++j) atomicAdd(&gp[j], o[j]);
                } else {                // non-root: compute outgoing msg (block-local)
                    float4 b4 = bond_s4[pos];
                    float m[INNER];
                    #pragma unroll
                    for (int j = 0; j < INNER; ++j)
                        m[j] = ib[j] + b4.x * iw[0 * INNER + j] + b4.y * iw[1 * INNER + j]
                                     + b4.z * iw[2 * INNER + j];
                    #pragma unroll
                    for (int k = 0; k < REC; ++k) {
                        float ok = o[k];
                        #pragma unroll
                        for (int j = 0; j < INNER; ++j) m[j] += ok * iw[(BOND + k) * INNER + j];
                    }
                    float4* mp = (float4*)(msg_s + (size_t)pos * REC);
                    #pragma unroll
                    for (int j = 0; j < 5; ++j)
                        mp[j] = make_float4(leaky(m[4*j]), leaky(m[4*j+1]),
                                            leaky(m[4*j+2]), leaky(m[4*j+3]));
                }
            }
        }
        // ---- leaves (bin b*32 + d*2 + 1) ----
        {
            int K = b * 32 + d * 2 + 1;
            int base = bin_base[K], n1 = bin_cnt[K];
            for (int idx = t; idx < n1; idx += NT2) {
                int pos = base + idx;
                int i  = node_list[pos];
                int gr = groot_s[pos];
                const float2* a2 = (const float2*)(atom + (size_t)i * ATOM);
                float a[ATOM];
                #pragma unroll
                for (int k = 0; k < 7; ++k) { float2 v = a2[k]; a[2*k] = v.x; a[2*k+1] = v.y; }
                float hid[HID];
                #pragma unroll
                for (int j = 0; j < HID; ++j) hid[j] = l0b1[j];
                for (int k = 0; k < ATOM; ++k) {
                    float ak = a[k];
                    #pragma unroll
                    for (int j = 0; j < HID; ++j) hid[j] += ak * l0w1[k * HID + j];
                }
                #pragma unroll
                for (int j = 0; j < HID; ++j) hid[j] = leaky(hid[j]);
                float o[REC];
                #pragma unroll
                for (int j = 0; j < REC; ++j) o[j] = l0b2[j];
                for (int k = 0; k < HID; ++k) {
                    float hk = hid[k];
                    #pragma unroll
                    for (int j = 0; j < REC; ++j) o[j] += hk * l0w2[k * REC + j];
                }
                #pragma unroll
                for (int j = 0; j < REC; ++j) o[j] = leaky(o[j]);
                if (gr >= 0) {
                    float* gp = g + (size_t)gr * REC;
                    #pragma unroll
                    for (int j = 0; j < REC; ++j) atomicAdd(&gp[j], o[j]);
                } else {
                    float4 b4 = bond_s4[pos];
                    float m[INNER];
                    #pragma unroll
                    for (int j = 0; j < INNER; ++j)
                        m[j] = ib[j] + b4.x * iw[0 * INNER + j] + b4.y * iw[1 * INNER + j]
                                     + b4.z * iw[2 * INNER + j];
                    #pragma unroll
                    for (int k = 0; k < REC; ++k) {
                        float ok = o[k];
                        #pragma unroll
                        for (int j = 0; j < INNER; ++j) m[j] += ok * iw[(BOND + k) * INNER + j];
                    }
                    float4* mp = (float4*)(msg_s + (size_t)pos * REC);
                    #pragma unroll
                    for (int j = 0; j < 5; ++j)
                        mp[j] = make_float4(leaky(m[4*j]), leaky(m[4*j+1]),
                                            leaky(m[4*j+2]), leaky(m[4*j+3]));
                }
            }
        }
        // block-local level barrier: same CU, plain mem ops, cheap
        __threadfence_block();
        __syncthreads();
    }
}

// ---------------- readout ----------------
__global__ void k_out(const float* __restrict__ g,
                      const float* __restrict__ w1, const float* __restrict__ b1,
                      const float* __restrict__ w2, const float* __restrict__ b2,
                      float* __restrict__ out) {
    int t = blockIdx.x * 256 + threadIdx.x;
    if (t >= NG) return;
    const float* gv = g + (size_t)t * REC;
    float gl[REC];
    #pragma unroll
    for (int k = 0; k < REC; ++k) gl[k] = gv[k];
    float acc = b2[0];
    for (int j = 0; j < OHID; ++j) {
        float s = b1[j];
        #pragma unroll
        for (int k = 0; k < REC; ++k) s += gl[k] * w1[k * OHID + j];
        acc += tanhf(s) * w2[j];
    }
    out[t] = acc;
}

extern "C" void kernel_launch(void* const* d_in, const int* in_sizes, int n_in,
                              void* d_out, int out_size, void* d_ws, size_t ws_size,
                              hipStream_t stream) {
    const float* atom    = (const float*)d_in[0];
    const float* bond    = (const float*)d_in[1];
    const int*   parent  = (const int*)d_in[2];
    const int*   child   = (const int*)d_in[3];
    const int*   depth   = (const int*)d_in[4];
    const int*   gid     = (const int*)d_in[5];
    const float* isr     = (const float*)d_in[6];
    const float* inner_w = (const float*)d_in[7];
    const float* inner_b = (const float*)d_in[8];
    const float* net_w1  = (const float*)d_in[9];
    const float* net_b1  = (const float*)d_in[10];
    const float* net_w2  = (const float*)d_in[11];
    const float* net_b2  = (const float*)d_in[12];
    const float* net0_w1 = (const float*)d_in[13];
    const float* net0_b1 = (const float*)d_in[14];
    const float* net0_w2 = (const float*)d_in[15];
    const float* net0_b2 = (const float*)d_in[16];
    const float* out_w1  = (const float*)d_in[17];
    const float* out_b1  = (const float*)d_in[18];
    const float* out_w2  = (const float*)d_in[19];
    const float* out_b2  = (const float*)d_in[20];
    float* out = (float*)d_out;

    char* ws = (char*)d_ws;
    size_t o = 0;
    float* msg_s    = (float*)(ws + o);  o += (size_t)NN * REC * 4;    // 83.9 MB
    float4* bond_s4 = (float4*)(ws + o); o += (size_t)NN * 16;         // 16.8 MB
    float* g        = (float*)(ws + o);  o += (size_t)NG * REC * 4;    // 1.3 MB
    int* adjc       = (int*)(ws + o);    o += (size_t)NE * 4;          // 3.9 MB
    int* cnt_n      = (int*)(ws + o);    o += (size_t)NN * 4;          // 4.2 MB (also cur2)
    int* pnode      = (int*)(ws + o);    o += (size_t)NN * 4;          // 4.2 MB (also node_list)
    int* r1         = (int*)(ws + o);    o += (size_t)NN * 4;          // 4.2 MB (also inv)
    int* r2         = (int*)(ws + o);    o += (size_t)NN * 4;          // 4.2 MB (also groot_s)
    int* K_s        = (int*)(ws + o);    o += (size_t)NN * 4;          // 4.2 MB
    int* cnt_s      = (int*)(ws + o);    o += (size_t)NN * 4;          // 4.2 MB
    int* row_ptr    = (int*)(ws + o);    o += (size_t)NN * 4;          // 4.2 MB
    int* bin_cnt    = (int*)(ws + o);    o += (size_t)NBINS * 4;       // 128 KB
    int* bin_base   = (int*)(ws + o);    o += (size_t)NBINS * 4;       // 128 KB
    int* bin_cur    = (int*)(ws + o);    o += (size_t)NBINS * 4;       // 128 KB
    int* totals     = (int*)(ws + o);    o += 32 * 4;
    int* bars       = (int*)(ws + o);    o += 32 * 4;
    // total ~136 MB

    k_pre<<<1024, 256, 0, stream>>>(cnt_n, pnode, g, bin_cnt, totals, bars);
    k_prep<<<NB, NT, 0, stream>>>(parent, child, depth, gid, isr, bond,
                                  cnt_n, pnode, r1, r2, K_s, cnt_s, row_ptr,
                                  adjc, bond_s4, bin_cnt, bin_base, bin_cur,
                                  totals, bars);
    k_levels<<<NB2, NT2, 0, stream>>>(atom, pnode /*node_list*/, r2 /*groot_s*/,
                                      cnt_s, row_ptr, adjc, bond_s4,
                                      bin_base, bin_cnt,
                                      inner_w, inner_b, net_w1, net_b1, net_w2, net_b2,
                                      net0_w1, net0_b1, net0_w2, net0_b2,
                                      g, msg_s);
    k_out<<<(NG + 255) / 256, 256, 0, stream>>>(g, out_w1, out_b1, out_w2, out_b2, out);
}

// Round 13
// 2180.006 us; speedup vs baseline: 4.1750x; 1.2572x over previous
//
#include <hip/hip_runtime.h>

#define ATOM  14
#define BOND  3
#define INNER 20
#define HID   34
#define HIDP  36             // HID padded to multiple of 4 for LDS rows
#define REC   20
#define OHID  25
#define NN    1048576
#define NE    983040
#define NG    16384

#define NB    512            // prep persistent grid
#define NT    256
#define GT    (NB*NT)        // 131072
#define SPAN  (NN/NB)        // 2048
#define SE    (SPAN/NT)      // 8

#define NB2   1024           // level blocks (independent, not cooperative)
#define NT2   128
#define NBINS (NB2*32)       // bin = blk*32 + depth*2 + isLeaf

__device__ __forceinline__ float leaky(float x) { return x >= 0.f ? x : 0.01f * x; }

// grid-wide barrier for prep only: device-scope fences (cross-XCD safe)
__device__ __forceinline__ void gbar_f(int* bar, int goal) {
    __syncthreads();
    if (threadIdx.x == 0) {
        __threadfence();
        __hip_atomic_fetch_add(bar, 1, __ATOMIC_RELEASE, __HIP_MEMORY_SCOPE_AGENT);
        while (__hip_atomic_load(bar, __ATOMIC_RELAXED, __HIP_MEMORY_SCOPE_AGENT) < goal)
            __builtin_amdgcn_s_sleep(32);
        __threadfence();
    }
    __syncthreads();
}

__global__ void k_pre(int* cnt_n, int* pnode, float* g, int* bin_cnt, int* totals, int* bars) {
    int tid = blockIdx.x * 256 + threadIdx.x;          // 262144 threads
    for (int i = tid; i < NN; i += 262144) { cnt_n[i] = 0; pnode[i] = i; }
    for (int i = tid; i < NG * REC; i += 262144) g[i] = 0.f;
    for (int i = tid; i < NBINS; i += 262144) bin_cnt[i] = 0;
    if (tid == 0) { totals[0] = 0; totals[16] = 0; }
    if (tid == 1) for (int k = 0; k < 32; ++k) bars[k] = 0;
}

// ---------------- prep: counts, roots, sort, CSR ----------------
__global__ __launch_bounds__(NT) void k_prep(
    const int* __restrict__ parent, const int* __restrict__ child,
    const int* __restrict__ depth, const int* __restrict__ gid,
    const float* __restrict__ isr, const float* __restrict__ bond,
    int* cnt_n,            // also cur2 (P8+)
    int* pnode,            // also node_list (P7+)
    int* r1,               // also inv (P7+)
    int* r2,               // also groot_s (P7+)
    int* K_s, int* cnt_s, int* row_ptr, int* adjc, float4* bond_s4,
    int* bin_cnt, int* bin_base, int* bin_cur,
    int* totals, int* bar)
{
    __shared__ int sh[NT];
    __shared__ int sbase_sh;
    const int t = threadIdx.x;
    const int tid = blockIdx.x * NT + t;
    int ep = 0;

    // P0: child counts + parent pointers
    for (int e = tid; e < NE; e += GT) {
        atomicAdd(&cnt_n[parent[e]], 1);
        pnode[child[e]] = parent[e];
    }
    gbar_f(bar, NB * ++ep);

    // P1-P4: pointer doubling -> r2 = root (covers 16 levels)
    for (int i = tid; i < NN; i += GT) r1[i] = pnode[pnode[i]];
    gbar_f(bar, NB * ++ep);
    for (int i = tid; i < NN; i += GT) r2[i] = r1[r1[i]];
    gbar_f(bar, NB * ++ep);
    for (int i = tid; i < NN; i += GT) r1[i] = r2[r2[i]];
    gbar_f(bar, NB * ++ep);
    for (int i = tid; i < NN; i += GT) r2[i] = r1[r1[i]];
    gbar_f(bar, NB * ++ep);

    // P5: bin key + histogram
    for (int i = tid; i < NN; i += GT) {
        int K = (r2[i] & (NB2 - 1)) * 32 + depth[i] * 2 + (cnt_n[i] == 0 ? 1 : 0);
        K_s[i] = K;
        atomicAdd(&bin_cnt[K], 1);
    }
    gbar_f(bar, NB * ++ep);

    // P6: bin scan (orderless base): blocks 0..127, 256 bins each
    if (blockIdx.x < NBINS / NT) {
        int k0 = blockIdx.x * NT + t;
        int v = bin_cnt[k0];
        sh[t] = v;
        __syncthreads();
        for (int ofs = 1; ofs < NT; ofs <<= 1) {
            int x = (t >= ofs) ? sh[t - ofs] : 0;
            __syncthreads();
            sh[t] += x;
            __syncthreads();
        }
        if (t == NT - 1) sbase_sh = atomicAdd(&totals[0], sh[t]);
        __syncthreads();
        int b = sbase_sh + sh[t] - v;
        bin_base[k0] = b;
        bin_cur[k0] = b;
    }
    gbar_f(bar, NB * ++ep);

    // P7: scatter (counting sort); NOTE node_list/inv/groot_s alias pnode/r1/r2
    for (int i = tid; i < NN; i += GT) {
        int pos = atomicAdd(&bin_cur[K_s[i]], 1);
        pnode[pos] = i;                                 // node_list
        r1[i] = pos;                                    // inv
        r2[pos] = (isr[i] != 0.f) ? gid[i] : -1;        // groot_s
        cnt_s[pos] = cnt_n[i];
    }
    gbar_f(bar, NB * ++ep);

    // P8: row_ptr via span scan + orderless base; cur2 (aliases cnt_n) = copy
    {
        int base0 = blockIdx.x * SPAN + t * SE;
        int v[SE]; int sum = 0;
        #pragma unroll
        for (int k = 0; k < SE; ++k) { v[k] = cnt_s[base0 + k]; sum += v[k]; }
        __syncthreads();
        sh[t] = sum;
        __syncthreads();
        for (int ofs = 1; ofs < NT; ofs <<= 1) {
            int x = (t >= ofs) ? sh[t - ofs] : 0;
            __syncthreads();
            sh[t] += x;
            __syncthreads();
        }
        if (t == NT - 1) sbase_sh = atomicAdd(&totals[16], sh[t]);
        __syncthreads();
        int run = sbase_sh + sh[t] - sum;
        #pragma unroll
        for (int k = 0; k < SE; ++k) { row_ptr[base0 + k] = run; cnt_n[base0 + k] = run; run += v[k]; }
    }
    gbar_f(bar, NB * ++ep);

    // P9: edge pass 2 — adjc fill + per-child bond
    for (int e = tid; e < NE; e += GT) {
        int cpos = r1[child[e]];                        // inv
        int pp   = r1[parent[e]];
        int slot = atomicAdd(&cnt_n[pp], 1);            // cur2
        adjc[slot] = cpos;
        bond_s4[cpos] = make_float4(bond[(size_t)e * BOND], bond[(size_t)e * BOND + 1],
                                    bond[(size_t)e * BOND + 2], 0.f);
    }
}

// ---------------- levels: independent blocks, LDS weights, 256-VGPR budget ----------------
__global__ __launch_bounds__(NT2, 2) void k_levels(
    const float* __restrict__ atom,
    const int* __restrict__ node_list, const int* __restrict__ groot_s,
    const int* __restrict__ cnt_s, const int* __restrict__ row_ptr,
    const int* __restrict__ adjc, const float4* __restrict__ bond_s4,
    const int* __restrict__ bin_base, const int* __restrict__ bin_cnt,
    const float* __restrict__ iw, const float* __restrict__ ib,
    const float* __restrict__ nw1, const float* __restrict__ nb1,
    const float* __restrict__ nw2, const float* __restrict__ nb2,
    const float* __restrict__ l0w1, const float* __restrict__ l0b1,
    const float* __restrict__ l0w2, const float* __restrict__ l0b2,
    float* __restrict__ g, float* __restrict__ msg_s)
{
    // ---- LDS weight cache (rows padded for aligned b128 broadcast reads) ----
    __shared__ float lw1[34 * HIDP];     // net_w1  [34][36]
    __shared__ float lw2[HID * REC];     // net_w2  [34][20]
    __shared__ float liw[23 * REC];      // inner_w [23][20]
    __shared__ float zw1[ATOM * HIDP];   // net0_w1 [14][36]
    __shared__ float zw2[HID * REC];     // net0_w2 [34][20]
    __shared__ float lb1[HID], lb2[REC], lbi[INNER], zb1[HID], zb2[REC];

    const int t = threadIdx.x;
    const int b = blockIdx.x;

    for (int idx = t; idx < 34 * HIDP; idx += NT2) {
        int r = idx / HIDP, c = idx - r * HIDP;
        lw1[idx] = (c < HID) ? nw1[r * HID + c] : 0.f;
    }
    for (int idx = t; idx < HID * REC; idx += NT2) { lw2[idx] = nw2[idx]; zw2[idx] = l0w2[idx]; }
    for (int idx = t; idx < 23 * REC; idx += NT2) liw[idx] = iw[idx];
    for (int idx = t; idx < ATOM * HIDP; idx += NT2) {
        int r = idx / HIDP, c = idx - r * HIDP;
        zw1[idx] = (c < HID) ? l0w1[r * HID + c] : 0.f;
    }
    if (t < HID) { lb1[t] = nb1[t]; zb1[t] = l0b1[t]; }
    else if (t >= 64 && t < 64 + REC) { lb2[t - 64] = nb2[t - 64]; zb2[t - 64] = l0b2[t - 64]; }
    if (t >= 96 && t < 96 + INNER) lbi[t - 96] = ib[t - 96];
    __syncthreads();

    for (int d = 15; d >= 0; --d) {
        // ---- internal nodes (bin b*32 + d*2) ----
        {
            int K = b * 32 + d * 2;
            int base = bin_base[K], n0 = bin_cnt[K];
            for (int idx = t; idx < n0; idx += NT2) {
                int pos = base + idx;
                int n   = cnt_s[pos];
                int i   = node_list[pos];
                int gr  = groot_s[pos];
                int rp0 = row_ptr[pos];
                const float2* a2 = (const float2*)(atom + (size_t)i * ATOM);
                float a[ATOM];
                #pragma unroll
                for (int k = 0; k < 7; ++k) { float2 v = a2[k]; a[2*k] = v.x; a[2*k+1] = v.y; }
                float isum[INNER];
                #pragma unroll
                for (int j = 0; j < INNER; ++j) isum[j] = 0.f;
                for (int r = rp0; r < rp0 + n; ++r) {
                    int c = adjc[r];
                    const float4* mp = (const float4*)(msg_s + (size_t)c * REC);
                    #pragma unroll
                    for (int q = 0; q < 5; ++q) {
                        float4 v = mp[q];
                        isum[4*q]   += v.x; isum[4*q+1] += v.y;
                        isum[4*q+2] += v.z; isum[4*q+3] += v.w;
                    }
                }
                float hid[HID];
                #pragma unroll
                for (int j = 0; j < HID; ++j) hid[j] = lb1[j];
                for (int k = 0; k < ATOM; ++k) {
                    float xk = a[k];
                    #pragma unroll
                    for (int j = 0; j < HID; ++j) hid[j] += xk * lw1[k * HIDP + j];
                }
                for (int k = 0; k < INNER; ++k) {
                    float xk = isum[k];
                    #pragma unroll
                    for (int j = 0; j < HID; ++j) hid[j] += xk * lw1[(ATOM + k) * HIDP + j];
                }
                #pragma unroll
                for (int j = 0; j < HID; ++j) hid[j] = leaky(hid[j]);
                float o[REC];
                #pragma unroll
                for (int j = 0; j < REC; ++j) o[j] = lb2[j];
                for (int k = 0; k < HID; ++k) {
                    float hk = hid[k];
                    #pragma unroll
                    for (int j = 0; j < REC; ++j) o[j] += hk * lw2[k * REC + j];
                }
                #pragma unroll
                for (int j = 0; j < REC; ++j) o[j] = leaky(o[j]);
                if (gr >= 0) {          // root: readout only
                    float* gp = g + (size_t)gr * REC;
                    #pragma unroll
                    for (int j = 0; j < REC; ++j) atomicAdd(&gp[j], o[j]);
                } else {                // non-root: outgoing msg
                    float4 b4 = bond_s4[pos];
                    float m[INNER];
                    #pragma unroll
                    for (int j = 0; j < INNER; ++j)
                        m[j] = lbi[j] + b4.x * liw[0 * INNER + j] + b4.y * liw[1 * INNER + j]
                                      + b4.z * liw[2 * INNER + j];
                    #pragma unroll
                    for (int k = 0; k < REC; ++k) {
                        float ok = o[k];
                        #pragma unroll
                        for (int j = 0; j < INNER; ++j) m[j] += ok * liw[(BOND + k) * INNER + j];
                    }
                    float4* mp = (float4*)(msg_s + (size_t)pos * REC);
                    #pragma unroll
                    for (int j = 0; j < 5; ++j)
                        mp[j] = make_float4(leaky(m[4*j]), leaky(m[4*j+1]),
                                            leaky(m[4*j+2]), leaky(m[4*j+3]));
                }
            }
        }
        // ---- leaves (bin b*32 + d*2 + 1) ----
        {
            int K = b * 32 + d * 2 + 1;
            int base = bin_base[K], n1 = bin_cnt[K];
            for (int idx = t; idx < n1; idx += NT2) {
                int pos = base + idx;
                int i  = node_list[pos];
                int gr = groot_s[pos];
                const float2* a2 = (const float2*)(atom + (size_t)i * ATOM);
                float a[ATOM];
                #pragma unroll
                for (int k = 0; k < 7; ++k) { float2 v = a2[k]; a[2*k] = v.x; a[2*k+1] = v.y; }
                float hid[HID];
                #pragma unroll
                for (int j = 0; j < HID; ++j) hid[j] = zb1[j];
                for (int k = 0; k < ATOM; ++k) {
                    float ak = a[k];
                    #pragma unroll
                    for (int j = 0; j < HID; ++j) hid[j] += ak * zw1[k * HIDP + j];
                }
                #pragma unroll
                for (int j = 0; j < HID; ++j) hid[j] = leaky(hid[j]);
                float o[REC];
                #pragma unroll
                for (int j = 0; j < REC; ++j) o[j] = zb2[j];
                for (int k = 0; k < HID; ++k) {
                    float hk = hid[k];
                    #pragma unroll
                    for (int j = 0; j < REC; ++j) o[j] += hk * zw2[k * REC + j];
                }
                #pragma unroll
                for (int j = 0; j < REC; ++j) o[j] = leaky(o[j]);
                if (gr >= 0) {
                    float* gp = g + (size_t)gr * REC;
                    #pragma unroll
                    for (int j = 0; j < REC; ++j) atomicAdd(&gp[j], o[j]);
                } else {
                    float4 b4 = bond_s4[pos];
                    float m[INNER];
                    #pragma unroll
                    for (int j = 0; j < INNER; ++j)
                        m[j] = lbi[j] + b4.x * liw[0 * INNER + j] + b4.y * liw[1 * INNER + j]
                                      + b4.z * liw[2 * INNER + j];
                    #pragma unroll
                    for (int k = 0; k < REC; ++k) {
                        float ok = o[k];
                        #pragma unroll
                        for (int j = 0; j < INNER; ++j) m[j] += ok * liw[(BOND + k) * INNER + j];
                    }
                    float4* mp = (float4*)(msg_s + (size_t)pos * REC);
                    #pragma unroll
                    for (int j = 0; j < 5; ++j)
                        mp[j] = make_float4(leaky(m[4*j]), leaky(m[4*j+1]),
                                            leaky(m[4*j+2]), leaky(m[4*j+3]));
                }
            }
        }
        // block-local level barrier
        __threadfence_block();
        __syncthreads();
    }
}

// ---------------- readout ----------------
__global__ void k_out(const float* __restrict__ g,
                      const float* __restrict__ w1, const float* __restrict__ b1,
                      const float* __restrict__ w2, const float* __restrict__ b2,
                      float* __restrict__ out) {
    int t = blockIdx.x * 256 + threadIdx.x;
    if (t >= NG) return;
    const float* gv = g + (size_t)t * REC;
    float gl[REC];
    #pragma unroll
    for (int k = 0; k < REC; ++k) gl[k] = gv[k];
    float acc = b2[0];
    for (int j = 0; j < OHID; ++j) {
        float s = b1[j];
        #pragma unroll
        for (int k = 0; k < REC; ++k) s += gl[k] * w1[k * OHID + j];
        acc += tanhf(s) * w2[j];
    }
    out[t] = acc;
}

extern "C" void kernel_launch(void* const* d_in, const int* in_sizes, int n_in,
                              void* d_out, int out_size, void* d_ws, size_t ws_size,
                              hipStream_t stream) {
    const float* atom    = (const float*)d_in[0];
    const float* bond    = (const float*)d_in[1];
    const int*   parent  = (const int*)d_in[2];
    const int*   child   = (const int*)d_in[3];
    const int*   depth   = (const int*)d_in[4];
    const int*   gid     = (const int*)d_in[5];
    const float* isr     = (const float*)d_in[6];
    const float* inner_w = (const float*)d_in[7];
    const float* inner_b = (const float*)d_in[8];
    const float* net_w1  = (const float*)d_in[9];
    const float* net_b1  = (const float*)d_in[10];
    const float* net_w2  = (const float*)d_in[11];
    const float* net_b2  = (const float*)d_in[12];
    const float* net0_w1 = (const float*)d_in[13];
    const float* net0_b1 = (const float*)d_in[14];
    const float* net0_w2 = (const float*)d_in[15];
    const float* net0_b2 = (const float*)d_in[16];
    const float* out_w1  = (const float*)d_in[17];
    const float* out_b1  = (const float*)d_in[18];
    const float* out_w2  = (const float*)d_in[19];
    const float* out_b2  = (const float*)d_in[20];
    float* out = (float*)d_out;

    char* ws = (char*)d_ws;
    size_t o = 0;
    float* msg_s    = (float*)(ws + o);  o += (size_t)NN * REC * 4;    // 83.9 MB
    float4* bond_s4 = (float4*)(ws + o); o += (size_t)NN * 16;         // 16.8 MB
    float* g        = (float*)(ws + o);  o += (size_t)NG * REC * 4;    // 1.3 MB
    int* adjc       = (int*)(ws + o);    o += (size_t)NE * 4;          // 3.9 MB
    int* cnt_n      = (int*)(ws + o);    o += (size_t)NN * 4;          // 4.2 MB (also cur2)
    int* pnode      = (int*)(ws + o);    o += (size_t)NN * 4;          // 4.2 MB (also node_list)
    int* r1         = (int*)(ws + o);    o += (size_t)NN * 4;          // 4.2 MB (also inv)
    int* r2         = (int*)(ws + o);    o += (size_t)NN * 4;          // 4.2 MB (also groot_s)
    int* K_s        = (int*)(ws + o);    o += (size_t)NN * 4;          // 4.2 MB
    int* cnt_s      = (int*)(ws + o);    o += (size_t)NN * 4;          // 4.2 MB
    int* row_ptr    = (int*)(ws + o);    o += (size_t)NN * 4;          // 4.2 MB
    int* bin_cnt    = (int*)(ws + o);    o += (size_t)NBINS * 4;       // 128 KB
    int* bin_base   = (int*)(ws + o);    o += (size_t)NBINS * 4;       // 128 KB
    int* bin_cur    = (int*)(ws + o);    o += (size_t)NBINS * 4;       // 128 KB
    int* totals     = (int*)(ws + o);    o += 32 * 4;
    int* bars       = (int*)(ws + o);    o += 32 * 4;
    // total ~136 MB

    k_pre<<<1024, 256, 0, stream>>>(cnt_n, pnode, g, bin_cnt, totals, bars);
    k_prep<<<NB, NT, 0, stream>>>(parent, child, depth, gid, isr, bond,
                                  cnt_n, pnode, r1, r2, K_s, cnt_s, row_ptr,
                                  adjc, bond_s4, bin_cnt, bin_base, bin_cur,
                                  totals, bars);
    k_levels<<<NB2, NT2, 0, stream>>>(atom, pnode /*node_list*/, r2 /*groot_s*/,
                                      cnt_s, row_ptr, adjc, bond_s4,
                                      bin_base, bin_cnt,
                                      inner_w, inner_b, net_w1, net_b1, net_w2, net_b2,
                                      net0_w1, net0_b1, net0_w2, net0_b2,
                                      g, msg_s);
    k_out<<<(NG + 255) / 256, 256, 0, stream>>>(g, out_w1, out_b1, out_w2, out_b2, out);
}